// Round 1
// baseline (853.905 us; speedup 1.0000x reference)
//
#include <hip/hip_runtime.h>

#define NN 50000
#define NE 400000
#define NG 64
#define D 256
#define DOUT 16

// ---------------- setup: degree, dinv, CSR by dst ----------------

__global__ void k_zero_cnt(int* cnt, int n) {
    int i = blockIdx.x * blockDim.x + threadIdx.x;
    if (i < n) cnt[i] = 0;
}

__global__ void k_count(const int* __restrict__ eidx, int* __restrict__ cnt, int E) {
    int e = blockIdx.x * blockDim.x + threadIdx.x;
    if (e < E) atomicAdd(&cnt[eidx[E + e]], 1);
}

__global__ void k_dinv(const int* __restrict__ cnt, float* __restrict__ dinv, int n) {
    int i = blockIdx.x * blockDim.x + threadIdx.x;
    if (i < n) dinv[i] = rsqrtf((float)(cnt[i] + 1));  // +1 self-loop; always > 0
}

// exclusive scan of cnt[n] -> row_ptr[n], 1024 elems/block
__global__ void k_scan1(const int* __restrict__ cnt, int* __restrict__ excl,
                        int* __restrict__ bsums, int n) {
    __shared__ int sh[256];
    int tid = threadIdx.x;
    int base = blockIdx.x * 1024;
    int v[4]; int tsum = 0;
    for (int j = 0; j < 4; ++j) {
        int i = base + tid * 4 + j;
        v[j] = (i < n) ? cnt[i] : 0;
        tsum += v[j];
    }
    sh[tid] = tsum; __syncthreads();
    for (int d = 1; d < 256; d <<= 1) {
        int t = (tid >= d) ? sh[tid - d] : 0;
        __syncthreads();
        sh[tid] += t;
        __syncthreads();
    }
    int run = sh[tid] - tsum;  // exclusive offset within block
    for (int j = 0; j < 4; ++j) {
        int i = base + tid * 4 + j;
        if (i < n) excl[i] = run;
        run += v[j];
    }
    if (tid == 255) bsums[blockIdx.x] = sh[255];
}

__global__ void k_scan2(int* bsums, int nb) {
    __shared__ int sh[64];
    int tid = threadIdx.x;
    int v = (tid < nb) ? bsums[tid] : 0;
    sh[tid] = v; __syncthreads();
    for (int d = 1; d < 64; d <<= 1) {
        int t = (tid >= d) ? sh[tid - d] : 0;
        __syncthreads();
        sh[tid] += t;
        __syncthreads();
    }
    if (tid < nb) bsums[tid] = sh[tid] - v;  // exclusive
}

__global__ void k_scan3(int* __restrict__ row_ptr, const int* __restrict__ bsums,
                        int* __restrict__ cursor, int n, int E) {
    int i = blockIdx.x * blockDim.x + threadIdx.x;
    if (i < n) {
        int v = row_ptr[i] + bsums[i >> 10];
        row_ptr[i] = v;
        cursor[i] = v;
    }
    if (i == 0) row_ptr[n] = E;
}

__global__ void k_fill(const int* __restrict__ eidx, int* __restrict__ cursor,
                       int* __restrict__ col_src, int E) {
    int e = blockIdx.x * blockDim.x + threadIdx.x;
    if (e < E) {
        int d = eidx[E + e];
        int pos = atomicAdd(&cursor[d], 1);
        col_src[pos] = eidx[e];
    }
}

// ---------------- fp32 GEMM: C[m] = (A @ B)[m] * dinv[m] ----------------
// M x 256 @ 256 x 256.  128x128 tile, 256 threads, 8x8 per thread.

#define BM 128
#define BN 128
#define BK 16

__global__ __launch_bounds__(256) void k_gemm_scaled(
        const float* __restrict__ A, const float* __restrict__ B,
        const float* __restrict__ dinv, float* __restrict__ C, int M) {
    __shared__ float As[BK][BM + 4];  // +4 keeps float4 alignment, breaks pow2 stride
    __shared__ float Bs[BK][BN];
    int tid = threadIdx.x;
    int bm = blockIdx.x * BM;
    int bn = blockIdx.y * BN;
    int trow = (tid >> 4) * 8;   // 0..120
    int tcol = (tid & 15) * 8;   // 0..120
    float acc[8][8] = {};

    int a_row = tid >> 2;          // 0..63 (+64 for 2nd half)
    int a_col = (tid & 3) * 4;     // k offset within chunk
    int b_row = tid >> 5;          // 0..7 (+8 for 2nd half)
    int b_col = (tid & 31) * 4;

    for (int k0 = 0; k0 < D; k0 += BK) {
        for (int half = 0; half < 2; ++half) {
            int r = a_row + half * 64;
            int grow = bm + r;
            float4 av = make_float4(0.f, 0.f, 0.f, 0.f);
            if (grow < M) av = *(const float4*)(A + (size_t)grow * D + k0 + a_col);
            As[a_col + 0][r] = av.x;
            As[a_col + 1][r] = av.y;
            As[a_col + 2][r] = av.z;
            As[a_col + 3][r] = av.w;
        }
        for (int half = 0; half < 2; ++half) {
            int r = b_row + half * 8;
            float4 bv = *(const float4*)(B + (size_t)(k0 + r) * D + bn + b_col);
            *(float4*)&Bs[r][b_col] = bv;
        }
        __syncthreads();
        for (int k = 0; k < BK; ++k) {
            float4 a0 = *(const float4*)&As[k][trow];
            float4 a1 = *(const float4*)&As[k][trow + 4];
            float4 b0 = *(const float4*)&Bs[k][tcol];
            float4 b1 = *(const float4*)&Bs[k][tcol + 4];
            float a[8] = {a0.x, a0.y, a0.z, a0.w, a1.x, a1.y, a1.z, a1.w};
            float b[8] = {b0.x, b0.y, b0.z, b0.w, b1.x, b1.y, b1.z, b1.w};
            for (int i = 0; i < 8; ++i)
                for (int j = 0; j < 8; ++j)
                    acc[i][j] += a[i] * b[j];
        }
        __syncthreads();
    }
    for (int i = 0; i < 8; ++i) {
        int grow = bm + trow + i;
        if (grow < M) {
            float s = dinv[grow];  // pre-scale rows by dinv: h' = (A@B)*dinv[row]
            float4* crow = (float4*)(C + (size_t)grow * D + bn + tcol);
            crow[0] = make_float4(acc[i][0] * s, acc[i][1] * s, acc[i][2] * s, acc[i][3] * s);
            crow[1] = make_float4(acc[i][4] * s, acc[i][5] * s, acc[i][6] * s, acc[i][7] * s);
        }
    }
}

// ---------------- aggregation: out[d] = relu(dinv[d]*(h'[d] + sum h'[src]) + b) ----
// one wave per node; lane i owns float4 at dim 4*i (64 lanes * 4 = 256 dims)

__global__ __launch_bounds__(256) void k_agg(
        const float* __restrict__ h, const float* __restrict__ dinv,
        const int* __restrict__ row_ptr, const int* __restrict__ col_src,
        const float* __restrict__ bias, float* __restrict__ out, int n) {
    int node = blockIdx.x * 4 + (threadIdx.x >> 6);
    if (node >= n) return;
    int lane = threadIdx.x & 63;
    float di = dinv[node];
    float4 acc = ((const float4*)(h + (size_t)node * D))[lane];  // self-loop (h already *dinv)
    int beg = row_ptr[node], end = row_ptr[node + 1];
    for (int e = beg; e < end; ++e) {
        int s = col_src[e];
        float4 hv = ((const float4*)(h + (size_t)s * D))[lane];
        acc.x += hv.x; acc.y += hv.y; acc.z += hv.z; acc.w += hv.w;
    }
    float4 b = ((const float4*)bias)[lane];
    acc.x = fmaxf(acc.x * di + b.x, 0.f);
    acc.y = fmaxf(acc.y * di + b.y, 0.f);
    acc.z = fmaxf(acc.z * di + b.z, 0.f);
    acc.w = fmaxf(acc.w * di + b.w, 0.f);
    ((float4*)(out + (size_t)node * D))[lane] = acc;
}

// ---------------- mean pool per graph (batch sorted) ----------------

__global__ void k_pool(const float* __restrict__ h, const int* __restrict__ batch,
                       float* __restrict__ pooled, int n) {
    int g = blockIdx.x;
    int t = threadIdx.x;  // 256 threads, one dim each
    int lo = 0, hi = n;
    while (lo < hi) { int mid = (lo + hi) >> 1; if (batch[mid] < g) lo = mid + 1; else hi = mid; }
    int start = lo;
    hi = n;
    while (lo < hi) { int mid = (lo + hi) >> 1; if (batch[mid] < g + 1) lo = mid + 1; else hi = mid; }
    int end = lo;
    float acc = 0.f;
    for (int i = start; i < end; ++i) acc += h[(size_t)i * D + t];
    float cnt = (float)(end - start);
    pooled[g * D + t] = acc / fmaxf(cnt, 1.f);
}

// ---------------- final FC: [64,256] @ [256,16] + b ----------------

__global__ void k_fc(const float* __restrict__ pooled, const float* __restrict__ W,
                     const float* __restrict__ b, float* __restrict__ out) {
    int t = blockIdx.x * blockDim.x + threadIdx.x;
    if (t >= NG * DOUT) return;
    int g = t >> 4, o = t & 15;
    float acc = b[o];
    for (int k = 0; k < D; ++k) acc += pooled[g * D + k] * W[k * DOUT + o];
    out[t] = acc;
}

// ---------------- launch ----------------

extern "C" void kernel_launch(void* const* d_in, const int* in_sizes, int n_in,
                              void* d_out, int out_size, void* d_ws, size_t ws_size,
                              hipStream_t stream) {
    const float* x    = (const float*)d_in[0];
    const int*   eidx = (const int*)d_in[1];
    const int*   batch= (const int*)d_in[2];
    const float* W1   = (const float*)d_in[3];
    const float* b1   = (const float*)d_in[4];
    const float* W2   = (const float*)d_in[5];
    const float* b2   = (const float*)d_in[6];
    const float* W3   = (const float*)d_in[7];
    const float* b3   = (const float*)d_in[8];
    const float* Wfc  = (const float*)d_in[9];
    const float* bfc  = (const float*)d_in[10];
    float* out = (float*)d_out;

    const int n = in_sizes[0] / D;      // 50000
    const int E = in_sizes[1] / 2;      // 400000

    // workspace layout (256B aligned slabs)
    char* p = (char*)d_ws;
    auto take = [&](size_t bytes) -> void* {
        void* q = (void*)p;
        p += (bytes + 255) & ~(size_t)255;
        return q;
    };
    int*   cnt     = (int*)take((size_t)n * 4);
    int*   row_ptr = (int*)take((size_t)(n + 1) * 4);
    int*   cursor  = (int*)take((size_t)n * 4);
    int*   col_src = (int*)take((size_t)E * 4);
    int*   bsums   = (int*)take(256 * 4);
    float* dinv    = (float*)take((size_t)n * 4);
    float* hbuf    = (float*)take((size_t)n * D * 4);
    float* abuf    = (float*)take((size_t)n * D * 4);
    float* pooled  = (float*)take((size_t)NG * D * 4);

    int tb = 256;
    int gn = (n + tb - 1) / tb;
    int ge = (E + tb - 1) / tb;
    int nb = (n + 1023) / 1024;   // 49 scan blocks

    k_zero_cnt<<<gn, tb, 0, stream>>>(cnt, n);
    k_count<<<ge, tb, 0, stream>>>(eidx, cnt, E);
    k_dinv<<<gn, tb, 0, stream>>>(cnt, dinv, n);
    k_scan1<<<nb, 256, 0, stream>>>(cnt, row_ptr, bsums, n);
    k_scan2<<<1, 64, 0, stream>>>(bsums, nb);
    k_scan3<<<gn, tb, 0, stream>>>(row_ptr, bsums, cursor, n, E);
    k_fill<<<ge, tb, 0, stream>>>(eidx, cursor, col_src, E);

    dim3 ggrid((n + BM - 1) / BM, D / BN);
    int agrid = (n + 3) / 4;

    k_gemm_scaled<<<ggrid, 256, 0, stream>>>(x, W1, dinv, hbuf, n);
    k_agg<<<agrid, 256, 0, stream>>>(hbuf, dinv, row_ptr, col_src, b1, abuf, n);

    k_gemm_scaled<<<ggrid, 256, 0, stream>>>(abuf, W2, dinv, hbuf, n);
    k_agg<<<agrid, 256, 0, stream>>>(hbuf, dinv, row_ptr, col_src, b2, abuf, n);

    k_gemm_scaled<<<ggrid, 256, 0, stream>>>(abuf, W3, dinv, hbuf, n);
    k_agg<<<agrid, 256, 0, stream>>>(hbuf, dinv, row_ptr, col_src, b3, abuf, n);

    k_pool<<<NG, 256, 0, stream>>>(abuf, batch, pooled, n);
    k_fc<<<4, 256, 0, stream>>>(pooled, Wfc, bfc, out);
}

// Round 2
// 688.468 us; speedup vs baseline: 1.2403x; 1.2403x over previous
//
#include <hip/hip_runtime.h>

#define NN 50000
#define NE 400000
#define NG 64
#define D 256
#define DOUT 16

// ---------------- setup: degree, dinv, CSR by dst ----------------

__global__ void k_zero_cnt(int* cnt, int n) {
    int i = blockIdx.x * blockDim.x + threadIdx.x;
    if (i < n) cnt[i] = 0;
}

__global__ void k_zero_f(float* p, int n) {
    int i = blockIdx.x * blockDim.x + threadIdx.x;
    if (i < n) p[i] = 0.f;
}

__global__ void k_count(const int* __restrict__ eidx, int* __restrict__ cnt, int E) {
    int e = blockIdx.x * blockDim.x + threadIdx.x;
    if (e < E) atomicAdd(&cnt[eidx[E + e]], 1);
}

__global__ void k_dinv(const int* __restrict__ cnt, float* __restrict__ dinv, int n) {
    int i = blockIdx.x * blockDim.x + threadIdx.x;
    if (i < n) dinv[i] = rsqrtf((float)(cnt[i] + 1));  // +1 self-loop; always > 0
}

// exclusive scan of cnt[n] -> row_ptr[n], 1024 elems/block
__global__ void k_scan1(const int* __restrict__ cnt, int* __restrict__ excl,
                        int* __restrict__ bsums, int n) {
    __shared__ int sh[256];
    int tid = threadIdx.x;
    int base = blockIdx.x * 1024;
    int v[4]; int tsum = 0;
    for (int j = 0; j < 4; ++j) {
        int i = base + tid * 4 + j;
        v[j] = (i < n) ? cnt[i] : 0;
        tsum += v[j];
    }
    sh[tid] = tsum; __syncthreads();
    for (int d = 1; d < 256; d <<= 1) {
        int t = (tid >= d) ? sh[tid - d] : 0;
        __syncthreads();
        sh[tid] += t;
        __syncthreads();
    }
    int run = sh[tid] - tsum;  // exclusive offset within block
    for (int j = 0; j < 4; ++j) {
        int i = base + tid * 4 + j;
        if (i < n) excl[i] = run;
        run += v[j];
    }
    if (tid == 255) bsums[blockIdx.x] = sh[255];
}

__global__ void k_scan2(int* bsums, int nb) {
    __shared__ int sh[64];
    int tid = threadIdx.x;
    int v = (tid < nb) ? bsums[tid] : 0;
    sh[tid] = v; __syncthreads();
    for (int d = 1; d < 64; d <<= 1) {
        int t = (tid >= d) ? sh[tid - d] : 0;
        __syncthreads();
        sh[tid] += t;
        __syncthreads();
    }
    if (tid < nb) bsums[tid] = sh[tid] - v;  // exclusive
}

__global__ void k_scan3(int* __restrict__ row_ptr, const int* __restrict__ bsums,
                        int* __restrict__ cursor, int n, int E) {
    int i = blockIdx.x * blockDim.x + threadIdx.x;
    if (i < n) {
        int v = row_ptr[i] + bsums[i >> 10];
        row_ptr[i] = v;
        cursor[i] = v;
    }
    if (i == 0) row_ptr[n] = E;
}

__global__ void k_fill(const int* __restrict__ eidx, int* __restrict__ cursor,
                       int* __restrict__ col_src, int E) {
    int e = blockIdx.x * blockDim.x + threadIdx.x;
    if (e < E) {
        int d = eidx[E + e];
        int pos = atomicAdd(&cursor[d], 1);
        col_src[pos] = eidx[e];
    }
}

// per-graph inverse counts from sorted batch (64 threads, binary search)
__global__ void k_gcnt(const int* __restrict__ batch, float* __restrict__ inv_cnt, int n) {
    int g = threadIdx.x;
    if (g >= NG) return;
    int lo = 0, hi = n;
    while (lo < hi) { int mid = (lo + hi) >> 1; if (batch[mid] < g) lo = mid + 1; else hi = mid; }
    int start = lo;
    hi = n;
    while (lo < hi) { int mid = (lo + hi) >> 1; if (batch[mid] < g + 1) lo = mid + 1; else hi = mid; }
    inv_cnt[g] = 1.f / fmaxf((float)(lo - start), 1.f);
}

// ---------------- fp32 GEMM: C[m] = (A @ B)[m] * dinv[m] ----------------
// M x 256 @ 256 x 256.  128x128 tile, 256 threads, 8x8 per thread.

#define BM 128
#define BN 128
#define BK 16

__global__ __launch_bounds__(256) void k_gemm_scaled(
        const float* __restrict__ A, const float* __restrict__ B,
        const float* __restrict__ dinv, float* __restrict__ C, int M) {
    __shared__ float As[BK][BM + 4];  // +4 keeps float4 alignment, breaks pow2 stride
    __shared__ float Bs[BK][BN];
    int tid = threadIdx.x;
    int bm = blockIdx.x * BM;
    int bn = blockIdx.y * BN;
    int trow = (tid >> 4) * 8;   // 0..120
    int tcol = (tid & 15) * 8;   // 0..120
    float acc[8][8] = {};

    int a_row = tid >> 2;          // 0..63 (+64 for 2nd half)
    int a_col = (tid & 3) * 4;     // k offset within chunk
    int b_row = tid >> 5;          // 0..7 (+8 for 2nd half)
    int b_col = (tid & 31) * 4;

    for (int k0 = 0; k0 < D; k0 += BK) {
        for (int half = 0; half < 2; ++half) {
            int r = a_row + half * 64;
            int grow = bm + r;
            float4 av = make_float4(0.f, 0.f, 0.f, 0.f);
            if (grow < M) av = *(const float4*)(A + (size_t)grow * D + k0 + a_col);
            As[a_col + 0][r] = av.x;
            As[a_col + 1][r] = av.y;
            As[a_col + 2][r] = av.z;
            As[a_col + 3][r] = av.w;
        }
        for (int half = 0; half < 2; ++half) {
            int r = b_row + half * 8;
            float4 bv = *(const float4*)(B + (size_t)(k0 + r) * D + bn + b_col);
            *(float4*)&Bs[r][b_col] = bv;
        }
        __syncthreads();
        for (int k = 0; k < BK; ++k) {
            float4 a0 = *(const float4*)&As[k][trow];
            float4 a1 = *(const float4*)&As[k][trow + 4];
            float4 b0 = *(const float4*)&Bs[k][tcol];
            float4 b1 = *(const float4*)&Bs[k][tcol + 4];
            float a[8] = {a0.x, a0.y, a0.z, a0.w, a1.x, a1.y, a1.z, a1.w};
            float b[8] = {b0.x, b0.y, b0.z, b0.w, b1.x, b1.y, b1.z, b1.w};
            for (int i = 0; i < 8; ++i)
                for (int j = 0; j < 8; ++j)
                    acc[i][j] += a[i] * b[j];
        }
        __syncthreads();
    }
    for (int i = 0; i < 8; ++i) {
        int grow = bm + trow + i;
        if (grow < M) {
            float s = dinv[grow];  // pre-scale rows by dinv: h' = (A@B)*dinv[row]
            float4* crow = (float4*)(C + (size_t)grow * D + bn + tcol);
            crow[0] = make_float4(acc[i][0] * s, acc[i][1] * s, acc[i][2] * s, acc[i][3] * s);
            crow[1] = make_float4(acc[i][4] * s, acc[i][5] * s, acc[i][6] * s, acc[i][7] * s);
        }
    }
}

// ---------------- aggregation: out[d] = relu(dinv[d]*(h'[d] + sum h'[src]) + b) ----
// one wave per node; lane i owns float4 at dim 4*i (64 lanes * 4 = 256 dims)

__global__ __launch_bounds__(256) void k_agg(
        const float* __restrict__ h, const float* __restrict__ dinv,
        const int* __restrict__ row_ptr, const int* __restrict__ col_src,
        const float* __restrict__ bias, float* __restrict__ out, int n) {
    int node = blockIdx.x * 4 + (threadIdx.x >> 6);
    if (node >= n) return;
    int lane = threadIdx.x & 63;
    float di = dinv[node];
    float4 acc = ((const float4*)(h + (size_t)node * D))[lane];  // self-loop (h already *dinv)
    int beg = row_ptr[node], end = row_ptr[node + 1];
    for (int e = beg; e < end; ++e) {
        int s = col_src[e];
        float4 hv = ((const float4*)(h + (size_t)s * D))[lane];
        acc.x += hv.x; acc.y += hv.y; acc.z += hv.z; acc.w += hv.w;
    }
    float4 b = ((const float4*)bias)[lane];
    acc.x = fmaxf(acc.x * di + b.x, 0.f);
    acc.y = fmaxf(acc.y * di + b.y, 0.f);
    acc.z = fmaxf(acc.z * di + b.z, 0.f);
    acc.w = fmaxf(acc.w * di + b.w, 0.f);
    ((float4*)(out + (size_t)node * D))[lane] = acc;
}

// ---------------- mean pool, stage 1: chunked sums + atomic flush ----------------
// 64 contiguous nodes per block; batch sorted -> ~1.08 graph spans per block.

__global__ __launch_bounds__(256) void k_pool_sum(
        const float* __restrict__ h, const int* __restrict__ batch,
        float* __restrict__ pooled, int n) {
    int beg = blockIdx.x * 64;
    if (beg >= n) return;
    int end = min(beg + 64, n);
    int t = threadIdx.x;  // dim t
    float acc = 0.f;
    int cur = batch[beg];
    for (int i = beg; i < end; ++i) {
        int g = batch[i];
        if (g != cur) {
            atomicAdd(&pooled[cur * D + t], acc);
            acc = 0.f;
            cur = g;
        }
        acc += h[(size_t)i * D + t];
    }
    atomicAdd(&pooled[cur * D + t], acc);
}

// ---------------- final FC: out[g,o] = bfc[o] + inv_cnt[g] * (pooled_sum[g] . W[:,o]) ----

__global__ void k_fc(const float* __restrict__ pooled, const float* __restrict__ inv_cnt,
                     const float* __restrict__ W, const float* __restrict__ b,
                     float* __restrict__ out) {
    int t = blockIdx.x * blockDim.x + threadIdx.x;
    if (t >= NG * DOUT) return;
    int g = t >> 4, o = t & 15;
    float acc = 0.f;
    for (int k = 0; k < D; ++k) acc += pooled[g * D + k] * W[k * DOUT + o];
    out[t] = acc * inv_cnt[g] + b[o];
}

// ---------------- launch ----------------

extern "C" void kernel_launch(void* const* d_in, const int* in_sizes, int n_in,
                              void* d_out, int out_size, void* d_ws, size_t ws_size,
                              hipStream_t stream) {
    const float* x    = (const float*)d_in[0];
    const int*   eidx = (const int*)d_in[1];
    const int*   batch= (const int*)d_in[2];
    const float* W1   = (const float*)d_in[3];
    const float* b1   = (const float*)d_in[4];
    const float* W2   = (const float*)d_in[5];
    const float* b2   = (const float*)d_in[6];
    const float* W3   = (const float*)d_in[7];
    const float* b3   = (const float*)d_in[8];
    const float* Wfc  = (const float*)d_in[9];
    const float* bfc  = (const float*)d_in[10];
    float* out = (float*)d_out;

    const int n = in_sizes[0] / D;      // 50000
    const int E = in_sizes[1] / 2;      // 400000

    // workspace layout (256B aligned slabs)
    char* p = (char*)d_ws;
    auto take = [&](size_t bytes) -> void* {
        void* q = (void*)p;
        p += (bytes + 255) & ~(size_t)255;
        return q;
    };
    int*   cnt     = (int*)take((size_t)n * 4);
    int*   row_ptr = (int*)take((size_t)(n + 1) * 4);
    int*   cursor  = (int*)take((size_t)n * 4);
    int*   col_src = (int*)take((size_t)E * 4);
    int*   bsums   = (int*)take(256 * 4);
    float* dinv    = (float*)take((size_t)n * 4);
    float* inv_cnt = (float*)take((size_t)NG * 4);
    float* hbuf    = (float*)take((size_t)n * D * 4);
    float* abuf    = (float*)take((size_t)n * D * 4);
    float* pooled  = (float*)take((size_t)NG * D * 4);

    int tb = 256;
    int gn = (n + tb - 1) / tb;
    int ge = (E + tb - 1) / tb;
    int nb = (n + 1023) / 1024;   // 49 scan blocks

    k_zero_cnt<<<gn, tb, 0, stream>>>(cnt, n);
    k_zero_f<<<(NG * D + 255) / 256, 256, 0, stream>>>(pooled, NG * D);
    k_gcnt<<<1, 64, 0, stream>>>(batch, inv_cnt, n);
    k_count<<<ge, tb, 0, stream>>>(eidx, cnt, E);
    k_dinv<<<gn, tb, 0, stream>>>(cnt, dinv, n);
    k_scan1<<<nb, 256, 0, stream>>>(cnt, row_ptr, bsums, n);
    k_scan2<<<1, 64, 0, stream>>>(bsums, nb);
    k_scan3<<<gn, tb, 0, stream>>>(row_ptr, bsums, cursor, n, E);
    k_fill<<<ge, tb, 0, stream>>>(eidx, cursor, col_src, E);

    dim3 ggrid((n + BM - 1) / BM, D / BN);
    int agrid = (n + 3) / 4;

    k_gemm_scaled<<<ggrid, 256, 0, stream>>>(x, W1, dinv, hbuf, n);
    k_agg<<<agrid, 256, 0, stream>>>(hbuf, dinv, row_ptr, col_src, b1, abuf, n);

    k_gemm_scaled<<<ggrid, 256, 0, stream>>>(abuf, W2, dinv, hbuf, n);
    k_agg<<<agrid, 256, 0, stream>>>(hbuf, dinv, row_ptr, col_src, b2, abuf, n);

    k_gemm_scaled<<<ggrid, 256, 0, stream>>>(abuf, W3, dinv, hbuf, n);
    k_agg<<<agrid, 256, 0, stream>>>(hbuf, dinv, row_ptr, col_src, b3, abuf, n);

    k_pool_sum<<<(n + 63) / 64, 256, 0, stream>>>(abuf, batch, pooled, n);
    k_fc<<<4, 256, 0, stream>>>(pooled, inv_cnt, Wfc, bfc, out);
}

// Round 3
// 526.167 us; speedup vs baseline: 1.6229x; 1.3085x over previous
//
#include <hip/hip_runtime.h>

#define NN 50000
#define NE 400000
#define NG 64
#define D 256
#define DOUT 16

typedef __attribute__((ext_vector_type(8))) short bf16x8;
typedef __attribute__((ext_vector_type(4))) float f32x4;

__device__ __forceinline__ short f2bf(float x) {
    union { float f; unsigned u; } v; v.f = x;
    unsigned r = v.u + 0x7fffu + ((v.u >> 16) & 1u);   // RNE
    return (short)(r >> 16);
}
__device__ __forceinline__ float bf2f(short h) {
    union { float f; unsigned u; } v;
    v.u = ((unsigned)(unsigned short)h) << 16;
    return v.f;
}

// ---------------- setup: degree, dinv, CSR by dst ----------------

__global__ void k_zero_cnt(int* cnt, int n) {
    int i = blockIdx.x * blockDim.x + threadIdx.x;
    if (i < n) cnt[i] = 0;
}

__global__ void k_zero_f(float* p, int n) {
    int i = blockIdx.x * blockDim.x + threadIdx.x;
    if (i < n) p[i] = 0.f;
}

__global__ void k_count(const int* __restrict__ eidx, int* __restrict__ cnt, int E) {
    int e = blockIdx.x * blockDim.x + threadIdx.x;
    if (e < E) atomicAdd(&cnt[eidx[E + e]], 1);
}

__global__ void k_dinv(const int* __restrict__ cnt, float* __restrict__ dinv, int n) {
    int i = blockIdx.x * blockDim.x + threadIdx.x;
    if (i < n) dinv[i] = rsqrtf((float)(cnt[i] + 1));  // +1 self-loop; always > 0
}

// exclusive scan of cnt[n] -> row_ptr[n], 1024 elems/block
__global__ void k_scan1(const int* __restrict__ cnt, int* __restrict__ excl,
                        int* __restrict__ bsums, int n) {
    __shared__ int sh[256];
    int tid = threadIdx.x;
    int base = blockIdx.x * 1024;
    int v[4]; int tsum = 0;
    for (int j = 0; j < 4; ++j) {
        int i = base + tid * 4 + j;
        v[j] = (i < n) ? cnt[i] : 0;
        tsum += v[j];
    }
    sh[tid] = tsum; __syncthreads();
    for (int d = 1; d < 256; d <<= 1) {
        int t = (tid >= d) ? sh[tid - d] : 0;
        __syncthreads();
        sh[tid] += t;
        __syncthreads();
    }
    int run = sh[tid] - tsum;  // exclusive offset within block
    for (int j = 0; j < 4; ++j) {
        int i = base + tid * 4 + j;
        if (i < n) excl[i] = run;
        run += v[j];
    }
    if (tid == 255) bsums[blockIdx.x] = sh[255];
}

__global__ void k_scan2(int* bsums, int nb) {
    __shared__ int sh[64];
    int tid = threadIdx.x;
    int v = (tid < nb) ? bsums[tid] : 0;
    sh[tid] = v; __syncthreads();
    for (int d = 1; d < 64; d <<= 1) {
        int t = (tid >= d) ? sh[tid - d] : 0;
        __syncthreads();
        sh[tid] += t;
        __syncthreads();
    }
    if (tid < nb) bsums[tid] = sh[tid] - v;  // exclusive
}

__global__ void k_scan3(int* __restrict__ row_ptr, const int* __restrict__ bsums,
                        int* __restrict__ cursor, int n, int E) {
    int i = blockIdx.x * blockDim.x + threadIdx.x;
    if (i < n) {
        int v = row_ptr[i] + bsums[i >> 10];
        row_ptr[i] = v;
        cursor[i] = v;
    }
    if (i == 0) row_ptr[n] = E;
}

__global__ void k_fill(const int* __restrict__ eidx, int* __restrict__ cursor,
                       int* __restrict__ col_src, int E) {
    int e = blockIdx.x * blockDim.x + threadIdx.x;
    if (e < E) {
        int d = eidx[E + e];
        int pos = atomicAdd(&cursor[d], 1);
        col_src[pos] = eidx[e];
    }
}

// per-graph inverse counts from sorted batch (64 threads, binary search)
__global__ void k_gcnt(const int* __restrict__ batch, float* __restrict__ inv_cnt, int n) {
    int g = threadIdx.x;
    if (g >= NG) return;
    int lo = 0, hi = n;
    while (lo < hi) { int mid = (lo + hi) >> 1; if (batch[mid] < g) lo = mid + 1; else hi = mid; }
    int start = lo;
    hi = n;
    while (lo < hi) { int mid = (lo + hi) >> 1; if (batch[mid] < g + 1) lo = mid + 1; else hi = mid; }
    inv_cnt[g] = 1.f / fmaxf((float)(lo - start), 1.f);
}

// ---------------- W -> W^T split into bf16 hi/lo: Wt[n][k] ----------------

__global__ void k_wsplit(const float* __restrict__ W, short* __restrict__ Whi,
                         short* __restrict__ Wlo) {
    int idx = blockIdx.x * 256 + threadIdx.x;  // idx = n*256 + k
    int n = idx >> 8, k = idx & 255;
    float x = W[k * 256 + n];
    short h = f2bf(x);
    Whi[idx] = h;
    Wlo[idx] = f2bf(x - bf2f(h));
}

// ---------------- MFMA split-bf16 GEMM: C[m] = (A @ B)[m] * dinv[m] ----------------
// A fp32 [M][256]; Wt hi/lo bf16 [256 n][256 k]. 128x128 tile, 4 waves of 64x64.
// A*B ~= Ahi*Bhi + Alo*Bhi + Ahi*Blo  (fp32 MFMA accumulate; lo*lo ~2^-18, dropped)

__global__ __launch_bounds__(256) void k_gemm_mfma(
        const float* __restrict__ A, const short* __restrict__ Whi,
        const short* __restrict__ Wlo, const float* __restrict__ dinv,
        float* __restrict__ C, int M) {
    // row stride 40 shorts = 80 B (odd dword multiple -> conflict-light ds_read_b128)
    __shared__ short As_h[128][40];
    __shared__ short As_l[128][40];
    __shared__ short Bs_h[128][40];
    __shared__ short Bs_l[128][40];

    const int tid = threadIdx.x;
    const int bm = blockIdx.x * 128;
    const int bn = blockIdx.y * 128;

    const int lane = tid & 63;
    const int w    = tid >> 6;
    const int wm   = w & 1;        // wave row (0-1)
    const int wn   = w >> 1;       // wave col (0-1)
    const int lm   = lane & 15;
    const int quad = lane >> 4;

    // staging map: thread covers row sr, 16 k's starting at sk
    const int sr = tid >> 1;
    const int sk = (tid & 1) * 16;

    f32x4 acc[4][4];
    #pragma unroll
    for (int i = 0; i < 4; ++i)
        #pragma unroll
        for (int j = 0; j < 4; ++j)
            acc[i][j] = (f32x4){0.f, 0.f, 0.f, 0.f};

    for (int k0 = 0; k0 < D; k0 += 32) {
        // ---- stage A (fp32 -> hi/lo bf16) ----
        {
            float f[16];
            int grow = bm + sr;
            if (grow < M) {
                const float* ap = A + (size_t)grow * D + k0 + sk;
                float4 v0 = *(const float4*)(ap);
                float4 v1 = *(const float4*)(ap + 4);
                float4 v2 = *(const float4*)(ap + 8);
                float4 v3 = *(const float4*)(ap + 12);
                f[0]=v0.x; f[1]=v0.y; f[2]=v0.z; f[3]=v0.w;
                f[4]=v1.x; f[5]=v1.y; f[6]=v1.z; f[7]=v1.w;
                f[8]=v2.x; f[9]=v2.y; f[10]=v2.z; f[11]=v2.w;
                f[12]=v3.x; f[13]=v3.y; f[14]=v3.z; f[15]=v3.w;
            } else {
                #pragma unroll
                for (int j = 0; j < 16; ++j) f[j] = 0.f;
            }
            bf16x8 h0, h1, l0, l1;
            #pragma unroll
            for (int j = 0; j < 8; ++j) {
                short h = f2bf(f[j]);
                h0[j] = h;
                l0[j] = f2bf(f[j] - bf2f(h));
            }
            #pragma unroll
            for (int j = 0; j < 8; ++j) {
                short h = f2bf(f[8 + j]);
                h1[j] = h;
                l1[j] = f2bf(f[8 + j] - bf2f(h));
            }
            *(bf16x8*)&As_h[sr][sk]     = h0;
            *(bf16x8*)&As_h[sr][sk + 8] = h1;
            *(bf16x8*)&As_l[sr][sk]     = l0;
            *(bf16x8*)&As_l[sr][sk + 8] = l1;
        }
        // ---- stage B^T (bf16 copy) ----
        {
            size_t off = ((size_t)(bn + sr) << 8) + k0 + sk;
            *(bf16x8*)&Bs_h[sr][sk]     = *(const bf16x8*)(Whi + off);
            *(bf16x8*)&Bs_h[sr][sk + 8] = *(const bf16x8*)(Whi + off + 8);
            *(bf16x8*)&Bs_l[sr][sk]     = *(const bf16x8*)(Wlo + off);
            *(bf16x8*)&Bs_l[sr][sk + 8] = *(const bf16x8*)(Wlo + off + 8);
        }
        __syncthreads();

        bf16x8 Ah[4], Al[4], Bh[4], Bl[4];
        #pragma unroll
        for (int mi = 0; mi < 4; ++mi) {
            int r = wm * 64 + mi * 16 + lm;
            Ah[mi] = *(const bf16x8*)&As_h[r][quad * 8];
            Al[mi] = *(const bf16x8*)&As_l[r][quad * 8];
        }
        #pragma unroll
        for (int ni = 0; ni < 4; ++ni) {
            int r = wn * 64 + ni * 16 + lm;
            Bh[ni] = *(const bf16x8*)&Bs_h[r][quad * 8];
            Bl[ni] = *(const bf16x8*)&Bs_l[r][quad * 8];
        }
        #pragma unroll
        for (int mi = 0; mi < 4; ++mi)
            #pragma unroll
            for (int ni = 0; ni < 4; ++ni) {
                acc[mi][ni] = __builtin_amdgcn_mfma_f32_16x16x32_bf16(Ah[mi], Bh[ni], acc[mi][ni], 0, 0, 0);
                acc[mi][ni] = __builtin_amdgcn_mfma_f32_16x16x32_bf16(Al[mi], Bh[ni], acc[mi][ni], 0, 0, 0);
                acc[mi][ni] = __builtin_amdgcn_mfma_f32_16x16x32_bf16(Ah[mi], Bl[ni], acc[mi][ni], 0, 0, 0);
            }
        __syncthreads();
    }

    // epilogue: C[row][col] = acc * dinv[row]
    #pragma unroll
    for (int mi = 0; mi < 4; ++mi) {
        int rbase = bm + wm * 64 + mi * 16 + quad * 4;
        #pragma unroll
        for (int r = 0; r < 4; ++r) {
            int grow = rbase + r;
            if (grow < M) {
                float s = dinv[grow];
                #pragma unroll
                for (int ni = 0; ni < 4; ++ni) {
                    int col = bn + wn * 64 + ni * 16 + lm;
                    C[(size_t)grow * D + col] = acc[mi][ni][r] * s;
                }
            }
        }
    }
}

// ---------------- aggregation: out[d] = relu(dinv[d]*(h'[d] + sum h'[src]) + b) ----
// one wave per node; lane i owns float4 at dim 4*i (64 lanes * 4 = 256 dims)

__global__ __launch_bounds__(256) void k_agg(
        const float* __restrict__ h, const float* __restrict__ dinv,
        const int* __restrict__ row_ptr, const int* __restrict__ col_src,
        const float* __restrict__ bias, float* __restrict__ out, int n) {
    int node = blockIdx.x * 4 + (threadIdx.x >> 6);
    if (node >= n) return;
    int lane = threadIdx.x & 63;
    float di = dinv[node];
    float4 acc = ((const float4*)(h + (size_t)node * D))[lane];  // self-loop (h already *dinv)
    int beg = row_ptr[node], end = row_ptr[node + 1];
    for (int e = beg; e < end; ++e) {
        int s = col_src[e];
        float4 hv = ((const float4*)(h + (size_t)s * D))[lane];
        acc.x += hv.x; acc.y += hv.y; acc.z += hv.z; acc.w += hv.w;
    }
    float4 b = ((const float4*)bias)[lane];
    acc.x = fmaxf(acc.x * di + b.x, 0.f);
    acc.y = fmaxf(acc.y * di + b.y, 0.f);
    acc.z = fmaxf(acc.z * di + b.z, 0.f);
    acc.w = fmaxf(acc.w * di + b.w, 0.f);
    ((float4*)(out + (size_t)node * D))[lane] = acc;
}

// ---------------- mean pool, stage 1: chunked sums + atomic flush ----------------
// 64 contiguous nodes per block; batch sorted -> ~1.08 graph spans per block.

__global__ __launch_bounds__(256) void k_pool_sum(
        const float* __restrict__ h, const int* __restrict__ batch,
        float* __restrict__ pooled, int n) {
    int beg = blockIdx.x * 64;
    if (beg >= n) return;
    int end = min(beg + 64, n);
    int t = threadIdx.x;  // dim t
    float acc = 0.f;
    int cur = batch[beg];
    for (int i = beg; i < end; ++i) {
        int g = batch[i];
        if (g != cur) {
            atomicAdd(&pooled[cur * D + t], acc);
            acc = 0.f;
            cur = g;
        }
        acc += h[(size_t)i * D + t];
    }
    atomicAdd(&pooled[cur * D + t], acc);
}

// ---------------- final FC: out[g,o] = bfc[o] + inv_cnt[g] * (pooled_sum[g] . W[:,o]) ----

__global__ void k_fc(const float* __restrict__ pooled, const float* __restrict__ inv_cnt,
                     const float* __restrict__ W, const float* __restrict__ b,
                     float* __restrict__ out) {
    int t = blockIdx.x * blockDim.x + threadIdx.x;
    if (t >= NG * DOUT) return;
    int g = t >> 4, o = t & 15;
    float acc = 0.f;
    for (int k = 0; k < D; ++k) acc += pooled[g * D + k] * W[k * DOUT + o];
    out[t] = acc * inv_cnt[g] + b[o];
}

// ---------------- launch ----------------

extern "C" void kernel_launch(void* const* d_in, const int* in_sizes, int n_in,
                              void* d_out, int out_size, void* d_ws, size_t ws_size,
                              hipStream_t stream) {
    const float* x    = (const float*)d_in[0];
    const int*   eidx = (const int*)d_in[1];
    const int*   batch= (const int*)d_in[2];
    const float* W1   = (const float*)d_in[3];
    const float* b1   = (const float*)d_in[4];
    const float* W2   = (const float*)d_in[5];
    const float* b2   = (const float*)d_in[6];
    const float* W3   = (const float*)d_in[7];
    const float* b3   = (const float*)d_in[8];
    const float* Wfc  = (const float*)d_in[9];
    const float* bfc  = (const float*)d_in[10];
    float* out = (float*)d_out;

    const int n = in_sizes[0] / D;      // 50000
    const int E = in_sizes[1] / 2;      // 400000

    // workspace layout (256B aligned slabs)
    char* p = (char*)d_ws;
    auto take = [&](size_t bytes) -> void* {
        void* q = (void*)p;
        p += (bytes + 255) & ~(size_t)255;
        return q;
    };
    int*   cnt     = (int*)take((size_t)n * 4);
    int*   row_ptr = (int*)take((size_t)(n + 1) * 4);
    int*   cursor  = (int*)take((size_t)n * 4);
    int*   col_src = (int*)take((size_t)E * 4);
    int*   bsums   = (int*)take(256 * 4);
    float* dinv    = (float*)take((size_t)n * 4);
    float* inv_cnt = (float*)take((size_t)NG * 4);
    short* w1hi    = (short*)take((size_t)D * D * 2);
    short* w1lo    = (short*)take((size_t)D * D * 2);
    short* w2hi    = (short*)take((size_t)D * D * 2);
    short* w2lo    = (short*)take((size_t)D * D * 2);
    short* w3hi    = (short*)take((size_t)D * D * 2);
    short* w3lo    = (short*)take((size_t)D * D * 2);
    float* hbuf    = (float*)take((size_t)n * D * 4);
    float* abuf    = (float*)take((size_t)n * D * 4);
    float* pooled  = (float*)take((size_t)NG * D * 4);

    int tb = 256;
    int gn = (n + tb - 1) / tb;
    int ge = (E + tb - 1) / tb;
    int nb = (n + 1023) / 1024;   // 49 scan blocks

    k_zero_cnt<<<gn, tb, 0, stream>>>(cnt, n);
    k_zero_f<<<(NG * D + 255) / 256, 256, 0, stream>>>(pooled, NG * D);
    k_gcnt<<<1, 64, 0, stream>>>(batch, inv_cnt, n);
    k_wsplit<<<D, 256, 0, stream>>>(W1, w1hi, w1lo);
    k_wsplit<<<D, 256, 0, stream>>>(W2, w2hi, w2lo);
    k_wsplit<<<D, 256, 0, stream>>>(W3, w3hi, w3lo);
    k_count<<<ge, tb, 0, stream>>>(eidx, cnt, E);
    k_dinv<<<gn, tb, 0, stream>>>(cnt, dinv, n);
    k_scan1<<<nb, 256, 0, stream>>>(cnt, row_ptr, bsums, n);
    k_scan2<<<1, 64, 0, stream>>>(bsums, nb);
    k_scan3<<<gn, tb, 0, stream>>>(row_ptr, bsums, cursor, n, E);
    k_fill<<<ge, tb, 0, stream>>>(eidx, cursor, col_src, E);

    dim3 ggrid((n + 127) / 128, 2);
    int agrid = (n + 3) / 4;

    k_gemm_mfma<<<ggrid, 256, 0, stream>>>(x, w1hi, w1lo, dinv, hbuf, n);
    k_agg<<<agrid, 256, 0, stream>>>(hbuf, dinv, row_ptr, col_src, b1, abuf, n);

    k_gemm_mfma<<<ggrid, 256, 0, stream>>>(abuf, w2hi, w2lo, dinv, hbuf, n);
    k_agg<<<agrid, 256, 0, stream>>>(hbuf, dinv, row_ptr, col_src, b2, abuf, n);

    k_gemm_mfma<<<ggrid, 256, 0, stream>>>(abuf, w3hi, w3lo, dinv, hbuf, n);
    k_agg<<<agrid, 256, 0, stream>>>(hbuf, dinv, row_ptr, col_src, b3, abuf, n);

    k_pool_sum<<<(n + 63) / 64, 256, 0, stream>>>(abuf, batch, pooled, n);
    k_fc<<<4, 256, 0, stream>>>(pooled, inv_cnt, Wfc, bfc, out);
}

// Round 4
// 479.642 us; speedup vs baseline: 1.7803x; 1.0970x over previous
//
#include <hip/hip_runtime.h>

#define NN 50000
#define NE 400000
#define NG 64
#define D 256
#define DOUT 16

typedef __attribute__((ext_vector_type(8))) short bf16x8;
typedef __attribute__((ext_vector_type(4))) float f32x4;

__device__ __forceinline__ short f2bf(float x) {
    union { float f; unsigned u; } v; v.f = x;
    unsigned r = v.u + 0x7fffu + ((v.u >> 16) & 1u);   // RNE
    return (short)(r >> 16);
}
__device__ __forceinline__ float bf2f(short h) {
    union { float f; unsigned u; } v;
    v.u = ((unsigned)(unsigned short)h) << 16;
    return v.f;
}

// ---------------- setup: degree, dinv, CSR by dst ----------------

__global__ void k_zero_cnt(int* cnt, int n) {
    int i = blockIdx.x * blockDim.x + threadIdx.x;
    if (i < n) cnt[i] = 0;
}

__global__ void k_zero_f(float* p, int n) {
    int i = blockIdx.x * blockDim.x + threadIdx.x;
    if (i < n) p[i] = 0.f;
}

__global__ void k_count(const int* __restrict__ eidx, int* __restrict__ cnt, int E) {
    int e = blockIdx.x * blockDim.x + threadIdx.x;
    if (e < E) atomicAdd(&cnt[eidx[E + e]], 1);
}

__global__ void k_dinv(const int* __restrict__ cnt, float* __restrict__ dinv, int n) {
    int i = blockIdx.x * blockDim.x + threadIdx.x;
    if (i < n) dinv[i] = rsqrtf((float)(cnt[i] + 1));  // +1 self-loop; always > 0
}

// exclusive scan of cnt[n] -> row_ptr[n], 1024 elems/block
__global__ void k_scan1(const int* __restrict__ cnt, int* __restrict__ excl,
                        int* __restrict__ bsums, int n) {
    __shared__ int sh[256];
    int tid = threadIdx.x;
    int base = blockIdx.x * 1024;
    int v[4]; int tsum = 0;
    for (int j = 0; j < 4; ++j) {
        int i = base + tid * 4 + j;
        v[j] = (i < n) ? cnt[i] : 0;
        tsum += v[j];
    }
    sh[tid] = tsum; __syncthreads();
    for (int d = 1; d < 256; d <<= 1) {
        int t = (tid >= d) ? sh[tid - d] : 0;
        __syncthreads();
        sh[tid] += t;
        __syncthreads();
    }
    int run = sh[tid] - tsum;  // exclusive offset within block
    for (int j = 0; j < 4; ++j) {
        int i = base + tid * 4 + j;
        if (i < n) excl[i] = run;
        run += v[j];
    }
    if (tid == 255) bsums[blockIdx.x] = sh[255];
}

__global__ void k_scan2(int* bsums, int nb) {
    __shared__ int sh[64];
    int tid = threadIdx.x;
    int v = (tid < nb) ? bsums[tid] : 0;
    sh[tid] = v; __syncthreads();
    for (int d = 1; d < 64; d <<= 1) {
        int t = (tid >= d) ? sh[tid - d] : 0;
        __syncthreads();
        sh[tid] += t;
        __syncthreads();
    }
    if (tid < nb) bsums[tid] = sh[tid] - v;  // exclusive
}

__global__ void k_scan3(int* __restrict__ row_ptr, const int* __restrict__ bsums,
                        int* __restrict__ cursor, int n, int E) {
    int i = blockIdx.x * blockDim.x + threadIdx.x;
    if (i < n) {
        int v = row_ptr[i] + bsums[i >> 10];
        row_ptr[i] = v;
        cursor[i] = v;
    }
    if (i == 0) row_ptr[n] = E;
}

__global__ void k_fill(const int* __restrict__ eidx, int* __restrict__ cursor,
                       int* __restrict__ col_src, int E) {
    int e = blockIdx.x * blockDim.x + threadIdx.x;
    if (e < E) {
        int d = eidx[E + e];
        int pos = atomicAdd(&cursor[d], 1);
        col_src[pos] = eidx[e];
    }
}

// per-graph inverse counts from sorted batch (64 threads, binary search)
__global__ void k_gcnt(const int* __restrict__ batch, float* __restrict__ inv_cnt, int n) {
    int g = threadIdx.x;
    if (g >= NG) return;
    int lo = 0, hi = n;
    while (lo < hi) { int mid = (lo + hi) >> 1; if (batch[mid] < g) lo = mid + 1; else hi = mid; }
    int start = lo;
    hi = n;
    while (lo < hi) { int mid = (lo + hi) >> 1; if (batch[mid] < g + 1) lo = mid + 1; else hi = mid; }
    inv_cnt[g] = 1.f / fmaxf((float)(lo - start), 1.f);
}

// ---------------- W -> W^T split into bf16 hi/lo: Wt[n][k] ----------------

__global__ void k_wsplit(const float* __restrict__ W, short* __restrict__ Whi,
                         short* __restrict__ Wlo) {
    int idx = blockIdx.x * 256 + threadIdx.x;  // idx = n*256 + k
    int n = idx >> 8, k = idx & 255;
    float x = W[k * 256 + n];
    short h = f2bf(x);
    Whi[idx] = h;
    Wlo[idx] = f2bf(x - bf2f(h));
}

// ---------------- MFMA split-bf16 GEMM: C[m] = bf16((A @ B)[m] * dinv[m]) ------
// A fp32 [M][256]; Wt hi/lo bf16 [256 n][256 k]. 128x128 tile, 4 waves of 64x64.
// A*B ~= Ahi*Bhi + Alo*Bhi + Ahi*Blo  (fp32 MFMA accumulate; lo*lo ~2^-18, dropped)

__global__ __launch_bounds__(256) void k_gemm_mfma(
        const float* __restrict__ A, const short* __restrict__ Whi,
        const short* __restrict__ Wlo, const float* __restrict__ dinv,
        unsigned short* __restrict__ C, int M) {
    // row stride 40 shorts = 80 B (odd dword multiple -> conflict-light ds_read_b128)
    __shared__ short As_h[128][40];
    __shared__ short As_l[128][40];
    __shared__ short Bs_h[128][40];
    __shared__ short Bs_l[128][40];

    const int tid = threadIdx.x;
    const int bm = blockIdx.x * 128;
    const int bn = blockIdx.y * 128;

    const int lane = tid & 63;
    const int w    = tid >> 6;
    const int wm   = w & 1;        // wave row (0-1)
    const int wn   = w >> 1;       // wave col (0-1)
    const int lm   = lane & 15;
    const int quad = lane >> 4;

    // staging map: thread covers row sr, 16 k's starting at sk
    const int sr = tid >> 1;
    const int sk = (tid & 1) * 16;

    f32x4 acc[4][4];
    #pragma unroll
    for (int i = 0; i < 4; ++i)
        #pragma unroll
        for (int j = 0; j < 4; ++j)
            acc[i][j] = (f32x4){0.f, 0.f, 0.f, 0.f};

    for (int k0 = 0; k0 < D; k0 += 32) {
        // ---- stage A (fp32 -> hi/lo bf16) ----
        {
            float f[16];
            int grow = bm + sr;
            if (grow < M) {
                const float* ap = A + (size_t)grow * D + k0 + sk;
                float4 v0 = *(const float4*)(ap);
                float4 v1 = *(const float4*)(ap + 4);
                float4 v2 = *(const float4*)(ap + 8);
                float4 v3 = *(const float4*)(ap + 12);
                f[0]=v0.x; f[1]=v0.y; f[2]=v0.z; f[3]=v0.w;
                f[4]=v1.x; f[5]=v1.y; f[6]=v1.z; f[7]=v1.w;
                f[8]=v2.x; f[9]=v2.y; f[10]=v2.z; f[11]=v2.w;
                f[12]=v3.x; f[13]=v3.y; f[14]=v3.z; f[15]=v3.w;
            } else {
                #pragma unroll
                for (int j = 0; j < 16; ++j) f[j] = 0.f;
            }
            bf16x8 h0, h1, l0, l1;
            #pragma unroll
            for (int j = 0; j < 8; ++j) {
                short h = f2bf(f[j]);
                h0[j] = h;
                l0[j] = f2bf(f[j] - bf2f(h));
            }
            #pragma unroll
            for (int j = 0; j < 8; ++j) {
                short h = f2bf(f[8 + j]);
                h1[j] = h;
                l1[j] = f2bf(f[8 + j] - bf2f(h));
            }
            *(bf16x8*)&As_h[sr][sk]     = h0;
            *(bf16x8*)&As_h[sr][sk + 8] = h1;
            *(bf16x8*)&As_l[sr][sk]     = l0;
            *(bf16x8*)&As_l[sr][sk + 8] = l1;
        }
        // ---- stage B^T (bf16 copy) ----
        {
            size_t off = ((size_t)(bn + sr) << 8) + k0 + sk;
            *(bf16x8*)&Bs_h[sr][sk]     = *(const bf16x8*)(Whi + off);
            *(bf16x8*)&Bs_h[sr][sk + 8] = *(const bf16x8*)(Whi + off + 8);
            *(bf16x8*)&Bs_l[sr][sk]     = *(const bf16x8*)(Wlo + off);
            *(bf16x8*)&Bs_l[sr][sk + 8] = *(const bf16x8*)(Wlo + off + 8);
        }
        __syncthreads();

        bf16x8 Ah[4], Al[4], Bh[4], Bl[4];
        #pragma unroll
        for (int mi = 0; mi < 4; ++mi) {
            int r = wm * 64 + mi * 16 + lm;
            Ah[mi] = *(const bf16x8*)&As_h[r][quad * 8];
            Al[mi] = *(const bf16x8*)&As_l[r][quad * 8];
        }
        #pragma unroll
        for (int ni = 0; ni < 4; ++ni) {
            int r = wn * 64 + ni * 16 + lm;
            Bh[ni] = *(const bf16x8*)&Bs_h[r][quad * 8];
            Bl[ni] = *(const bf16x8*)&Bs_l[r][quad * 8];
        }
        #pragma unroll
        for (int mi = 0; mi < 4; ++mi)
            #pragma unroll
            for (int ni = 0; ni < 4; ++ni) {
                acc[mi][ni] = __builtin_amdgcn_mfma_f32_16x16x32_bf16(Ah[mi], Bh[ni], acc[mi][ni], 0, 0, 0);
                acc[mi][ni] = __builtin_amdgcn_mfma_f32_16x16x32_bf16(Al[mi], Bh[ni], acc[mi][ni], 0, 0, 0);
                acc[mi][ni] = __builtin_amdgcn_mfma_f32_16x16x32_bf16(Ah[mi], Bl[ni], acc[mi][ni], 0, 0, 0);
            }
        __syncthreads();
    }

    // epilogue: C[row][col] = bf16(acc * dinv[row])
    #pragma unroll
    for (int mi = 0; mi < 4; ++mi) {
        int rbase = bm + wm * 64 + mi * 16 + quad * 4;
        #pragma unroll
        for (int r = 0; r < 4; ++r) {
            int grow = rbase + r;
            if (grow < M) {
                float s = dinv[grow];
                #pragma unroll
                for (int ni = 0; ni < 4; ++ni) {
                    int col = bn + wn * 64 + ni * 16 + lm;
                    C[(size_t)grow * D + col] = (unsigned short)f2bf(acc[mi][ni][r] * s);
                }
            }
        }
    }
}

// ---------------- aggregation: out[d] = relu(dinv[d]*(h'[d] + sum h'[src]) + b) ----
// h' is bf16; one wave per node; lane i owns dims 4i..4i+3 (ushort4 = 8 B/row/lane)

__global__ __launch_bounds__(256) void k_agg(
        const unsigned short* __restrict__ h, const float* __restrict__ dinv,
        const int* __restrict__ row_ptr, const int* __restrict__ col_src,
        const float* __restrict__ bias, float* __restrict__ out, int n) {
    int node = blockIdx.x * 4 + (threadIdx.x >> 6);
    if (node >= n) return;
    int lane = threadIdx.x & 63;
    float di = dinv[node];
    ushort4 sv = ((const ushort4*)(h + (size_t)node * D))[lane];  // self-loop
    float4 acc = make_float4(bf2f(sv.x), bf2f(sv.y), bf2f(sv.z), bf2f(sv.w));
    int beg = row_ptr[node], end = row_ptr[node + 1];
    for (int e = beg; e < end; ++e) {
        int s = col_src[e];
        ushort4 hv = ((const ushort4*)(h + (size_t)s * D))[lane];
        acc.x += bf2f(hv.x); acc.y += bf2f(hv.y);
        acc.z += bf2f(hv.z); acc.w += bf2f(hv.w);
    }
    float4 b = ((const float4*)bias)[lane];
    acc.x = fmaxf(acc.x * di + b.x, 0.f);
    acc.y = fmaxf(acc.y * di + b.y, 0.f);
    acc.z = fmaxf(acc.z * di + b.z, 0.f);
    acc.w = fmaxf(acc.w * di + b.w, 0.f);
    ((float4*)(out + (size_t)node * D))[lane] = acc;
}

// ---------------- mean pool, stage 1: chunked sums + atomic flush ----------------
// 64 contiguous nodes per block; batch sorted -> ~1.08 graph spans per block.

__global__ __launch_bounds__(256) void k_pool_sum(
        const float* __restrict__ h, const int* __restrict__ batch,
        float* __restrict__ pooled, int n) {
    int beg = blockIdx.x * 64;
    if (beg >= n) return;
    int end = min(beg + 64, n);
    int t = threadIdx.x;  // dim t
    float acc = 0.f;
    int cur = batch[beg];
    for (int i = beg; i < end; ++i) {
        int g = batch[i];
        if (g != cur) {
            atomicAdd(&pooled[cur * D + t], acc);
            acc = 0.f;
            cur = g;
        }
        acc += h[(size_t)i * D + t];
    }
    atomicAdd(&pooled[cur * D + t], acc);
}

// ---------------- final FC: out[g,o] = bfc[o] + inv_cnt[g] * (pooled_sum[g] . W[:,o]) ----

__global__ void k_fc(const float* __restrict__ pooled, const float* __restrict__ inv_cnt,
                     const float* __restrict__ W, const float* __restrict__ b,
                     float* __restrict__ out) {
    int t = blockIdx.x * blockDim.x + threadIdx.x;
    if (t >= NG * DOUT) return;
    int g = t >> 4, o = t & 15;
    float acc = 0.f;
    for (int k = 0; k < D; ++k) acc += pooled[g * D + k] * W[k * DOUT + o];
    out[t] = acc * inv_cnt[g] + b[o];
}

// ---------------- launch ----------------

extern "C" void kernel_launch(void* const* d_in, const int* in_sizes, int n_in,
                              void* d_out, int out_size, void* d_ws, size_t ws_size,
                              hipStream_t stream) {
    const float* x    = (const float*)d_in[0];
    const int*   eidx = (const int*)d_in[1];
    const int*   batch= (const int*)d_in[2];
    const float* W1   = (const float*)d_in[3];
    const float* b1   = (const float*)d_in[4];
    const float* W2   = (const float*)d_in[5];
    const float* b2   = (const float*)d_in[6];
    const float* W3   = (const float*)d_in[7];
    const float* b3   = (const float*)d_in[8];
    const float* Wfc  = (const float*)d_in[9];
    const float* bfc  = (const float*)d_in[10];
    float* out = (float*)d_out;

    const int n = in_sizes[0] / D;      // 50000
    const int E = in_sizes[1] / 2;      // 400000

    // workspace layout (256B aligned slabs)
    char* p = (char*)d_ws;
    auto take = [&](size_t bytes) -> void* {
        void* q = (void*)p;
        p += (bytes + 255) & ~(size_t)255;
        return q;
    };
    int*   cnt     = (int*)take((size_t)n * 4);
    int*   row_ptr = (int*)take((size_t)(n + 1) * 4);
    int*   cursor  = (int*)take((size_t)n * 4);
    int*   col_src = (int*)take((size_t)E * 4);
    int*   bsums   = (int*)take(256 * 4);
    float* dinv    = (float*)take((size_t)n * 4);
    float* inv_cnt = (float*)take((size_t)NG * 4);
    short* w1hi    = (short*)take((size_t)D * D * 2);
    short* w1lo    = (short*)take((size_t)D * D * 2);
    short* w2hi    = (short*)take((size_t)D * D * 2);
    short* w2lo    = (short*)take((size_t)D * D * 2);
    short* w3hi    = (short*)take((size_t)D * D * 2);
    short* w3lo    = (short*)take((size_t)D * D * 2);
    unsigned short* hbuf = (unsigned short*)take((size_t)n * D * 2);  // bf16 h'
    float* abuf    = (float*)take((size_t)n * D * 4);
    float* pooled  = (float*)take((size_t)NG * D * 4);

    int tb = 256;
    int gn = (n + tb - 1) / tb;
    int ge = (E + tb - 1) / tb;
    int nb = (n + 1023) / 1024;   // 49 scan blocks

    k_zero_cnt<<<gn, tb, 0, stream>>>(cnt, n);
    k_zero_f<<<(NG * D + 255) / 256, 256, 0, stream>>>(pooled, NG * D);
    k_gcnt<<<1, 64, 0, stream>>>(batch, inv_cnt, n);
    k_wsplit<<<D, 256, 0, stream>>>(W1, w1hi, w1lo);
    k_wsplit<<<D, 256, 0, stream>>>(W2, w2hi, w2lo);
    k_wsplit<<<D, 256, 0, stream>>>(W3, w3hi, w3lo);
    k_count<<<ge, tb, 0, stream>>>(eidx, cnt, E);
    k_dinv<<<gn, tb, 0, stream>>>(cnt, dinv, n);
    k_scan1<<<nb, 256, 0, stream>>>(cnt, row_ptr, bsums, n);
    k_scan2<<<1, 64, 0, stream>>>(bsums, nb);
    k_scan3<<<gn, tb, 0, stream>>>(row_ptr, bsums, cursor, n, E);
    k_fill<<<ge, tb, 0, stream>>>(eidx, cursor, col_src, E);

    dim3 ggrid((n + 127) / 128, 2);
    int agrid = (n + 3) / 4;

    k_gemm_mfma<<<ggrid, 256, 0, stream>>>(x, w1hi, w1lo, dinv, hbuf, n);
    k_agg<<<agrid, 256, 0, stream>>>(hbuf, dinv, row_ptr, col_src, b1, abuf, n);

    k_gemm_mfma<<<ggrid, 256, 0, stream>>>(abuf, w2hi, w2lo, dinv, hbuf, n);
    k_agg<<<agrid, 256, 0, stream>>>(hbuf, dinv, row_ptr, col_src, b2, abuf, n);

    k_gemm_mfma<<<ggrid, 256, 0, stream>>>(abuf, w3hi, w3lo, dinv, hbuf, n);
    k_agg<<<agrid, 256, 0, stream>>>(hbuf, dinv, row_ptr, col_src, b3, abuf, n);

    k_pool_sum<<<(n + 63) / 64, 256, 0, stream>>>(abuf, batch, pooled, n);
    k_fc<<<4, 256, 0, stream>>>(pooled, inv_cnt, Wfc, bfc, out);
}

// Round 5
// 450.658 us; speedup vs baseline: 1.8948x; 1.0643x over previous
//
#include <hip/hip_runtime.h>

#define NN 50000
#define NE 400000
#define NG 64
#define D 256
#define DOUT 16

typedef __attribute__((ext_vector_type(8))) short bf16x8;
typedef __attribute__((ext_vector_type(4))) float f32x4;

__device__ __forceinline__ short f2bf(float x) {
    union { float f; unsigned u; } v; v.f = x;
    unsigned r = v.u + 0x7fffu + ((v.u >> 16) & 1u);   // RNE
    return (short)(r >> 16);
}
__device__ __forceinline__ float bf2f(short h) {
    union { float f; unsigned u; } v;
    v.u = ((unsigned)(unsigned short)h) << 16;
    return v.f;
}

// ---------------- setup: degree, dinv, CSR by dst ----------------

__global__ void k_zero_cnt(int* cnt, int n) {
    int i = blockIdx.x * blockDim.x + threadIdx.x;
    if (i < n) cnt[i] = 0;
}

__global__ void k_zero_f(float* p, int n) {
    int i = blockIdx.x * blockDim.x + threadIdx.x;
    if (i < n) p[i] = 0.f;
}

__global__ void k_count(const int* __restrict__ eidx, int* __restrict__ cnt, int E) {
    int e = blockIdx.x * blockDim.x + threadIdx.x;
    if (e < E) atomicAdd(&cnt[eidx[E + e]], 1);
}

__global__ void k_dinv(const int* __restrict__ cnt, float* __restrict__ dinv, int n) {
    int i = blockIdx.x * blockDim.x + threadIdx.x;
    if (i < n) dinv[i] = rsqrtf((float)(cnt[i] + 1));  // +1 self-loop; always > 0
}

// exclusive scan of cnt[n] -> row_ptr[n], 1024 elems/block
__global__ void k_scan1(const int* __restrict__ cnt, int* __restrict__ excl,
                        int* __restrict__ bsums, int n) {
    __shared__ int sh[256];
    int tid = threadIdx.x;
    int base = blockIdx.x * 1024;
    int v[4]; int tsum = 0;
    for (int j = 0; j < 4; ++j) {
        int i = base + tid * 4 + j;
        v[j] = (i < n) ? cnt[i] : 0;
        tsum += v[j];
    }
    sh[tid] = tsum; __syncthreads();
    for (int d = 1; d < 256; d <<= 1) {
        int t = (tid >= d) ? sh[tid - d] : 0;
        __syncthreads();
        sh[tid] += t;
        __syncthreads();
    }
    int run = sh[tid] - tsum;  // exclusive offset within block
    for (int j = 0; j < 4; ++j) {
        int i = base + tid * 4 + j;
        if (i < n) excl[i] = run;
        run += v[j];
    }
    if (tid == 255) bsums[blockIdx.x] = sh[255];
}

__global__ void k_scan2(int* bsums, int nb) {
    __shared__ int sh[64];
    int tid = threadIdx.x;
    int v = (tid < nb) ? bsums[tid] : 0;
    sh[tid] = v; __syncthreads();
    for (int d = 1; d < 64; d <<= 1) {
        int t = (tid >= d) ? sh[tid - d] : 0;
        __syncthreads();
        sh[tid] += t;
        __syncthreads();
    }
    if (tid < nb) bsums[tid] = sh[tid] - v;  // exclusive
}

__global__ void k_scan3(int* __restrict__ row_ptr, const int* __restrict__ bsums,
                        int* __restrict__ cursor, int n, int E) {
    int i = blockIdx.x * blockDim.x + threadIdx.x;
    if (i < n) {
        int v = row_ptr[i] + bsums[i >> 10];
        row_ptr[i] = v;
        cursor[i] = v;
    }
    if (i == 0) row_ptr[n] = E;
}

__global__ void k_fill(const int* __restrict__ eidx, int* __restrict__ cursor,
                       int* __restrict__ col_src, int E) {
    int e = blockIdx.x * blockDim.x + threadIdx.x;
    if (e < E) {
        int d = eidx[E + e];
        int pos = atomicAdd(&cursor[d], 1);
        col_src[pos] = eidx[e];
    }
}

// per-graph inverse counts from sorted batch (64 threads, binary search)
__global__ void k_gcnt(const int* __restrict__ batch, float* __restrict__ inv_cnt, int n) {
    int g = threadIdx.x;
    if (g >= NG) return;
    int lo = 0, hi = n;
    while (lo < hi) { int mid = (lo + hi) >> 1; if (batch[mid] < g) lo = mid + 1; else hi = mid; }
    int start = lo;
    hi = n;
    while (lo < hi) { int mid = (lo + hi) >> 1; if (batch[mid] < g + 1) lo = mid + 1; else hi = mid; }
    inv_cnt[g] = 1.f / fmaxf((float)(lo - start), 1.f);
}

// ---------------- W -> W^T split into bf16 hi/lo: Wt[n][k] ----------------

__global__ void k_wsplit(const float* __restrict__ W, short* __restrict__ Whi,
                         short* __restrict__ Wlo) {
    int idx = blockIdx.x * 256 + threadIdx.x;  // idx = n*256 + k
    int n = idx >> 8, k = idx & 255;
    float x = W[k * 256 + n];
    short h = f2bf(x);
    Whi[idx] = h;
    Wlo[idx] = f2bf(x - bf2f(h));
}

// ---------------- MFMA split-bf16 GEMM: C[m] = bf16((A @ B)[m] * dinv[m]) ------
// A fp32 [M][256]; Wt hi/lo bf16 [256 n][256 k]. 128x128 tile, 4 waves of 64x64.
// A*B ~= Ahi*Bhi + Alo*Bhi + Ahi*Blo  (fp32 MFMA accumulate; lo*lo ~2^-18, dropped)

__global__ __launch_bounds__(256) void k_gemm_mfma(
        const float* __restrict__ A, const short* __restrict__ Whi,
        const short* __restrict__ Wlo, const float* __restrict__ dinv,
        unsigned short* __restrict__ C, int M) {
    // row stride 40 shorts = 80 B (odd dword multiple -> conflict-light ds_read_b128)
    __shared__ short As_h[128][40];
    __shared__ short As_l[128][40];
    __shared__ short Bs_h[128][40];
    __shared__ short Bs_l[128][40];

    const int tid = threadIdx.x;
    const int bm = blockIdx.x * 128;
    const int bn = blockIdx.y * 128;

    const int lane = tid & 63;
    const int w    = tid >> 6;
    const int wm   = w & 1;        // wave row (0-1)
    const int wn   = w >> 1;       // wave col (0-1)
    const int lm   = lane & 15;
    const int quad = lane >> 4;

    // staging map: thread covers row sr, 16 k's starting at sk
    const int sr = tid >> 1;
    const int sk = (tid & 1) * 16;

    f32x4 acc[4][4];
    #pragma unroll
    for (int i = 0; i < 4; ++i)
        #pragma unroll
        for (int j = 0; j < 4; ++j)
            acc[i][j] = (f32x4){0.f, 0.f, 0.f, 0.f};

    for (int k0 = 0; k0 < D; k0 += 32) {
        // ---- stage A (fp32 -> hi/lo bf16) ----
        {
            float f[16];
            int grow = bm + sr;
            if (grow < M) {
                const float* ap = A + (size_t)grow * D + k0 + sk;
                float4 v0 = *(const float4*)(ap);
                float4 v1 = *(const float4*)(ap + 4);
                float4 v2 = *(const float4*)(ap + 8);
                float4 v3 = *(const float4*)(ap + 12);
                f[0]=v0.x; f[1]=v0.y; f[2]=v0.z; f[3]=v0.w;
                f[4]=v1.x; f[5]=v1.y; f[6]=v1.z; f[7]=v1.w;
                f[8]=v2.x; f[9]=v2.y; f[10]=v2.z; f[11]=v2.w;
                f[12]=v3.x; f[13]=v3.y; f[14]=v3.z; f[15]=v3.w;
            } else {
                #pragma unroll
                for (int j = 0; j < 16; ++j) f[j] = 0.f;
            }
            bf16x8 h0, h1, l0, l1;
            #pragma unroll
            for (int j = 0; j < 8; ++j) {
                short h = f2bf(f[j]);
                h0[j] = h;
                l0[j] = f2bf(f[j] - bf2f(h));
            }
            #pragma unroll
            for (int j = 0; j < 8; ++j) {
                short h = f2bf(f[8 + j]);
                h1[j] = h;
                l1[j] = f2bf(f[8 + j] - bf2f(h));
            }
            *(bf16x8*)&As_h[sr][sk]     = h0;
            *(bf16x8*)&As_h[sr][sk + 8] = h1;
            *(bf16x8*)&As_l[sr][sk]     = l0;
            *(bf16x8*)&As_l[sr][sk + 8] = l1;
        }
        // ---- stage B^T (bf16 copy) ----
        {
            size_t off = ((size_t)(bn + sr) << 8) + k0 + sk;
            *(bf16x8*)&Bs_h[sr][sk]     = *(const bf16x8*)(Whi + off);
            *(bf16x8*)&Bs_h[sr][sk + 8] = *(const bf16x8*)(Whi + off + 8);
            *(bf16x8*)&Bs_l[sr][sk]     = *(const bf16x8*)(Wlo + off);
            *(bf16x8*)&Bs_l[sr][sk + 8] = *(const bf16x8*)(Wlo + off + 8);
        }
        __syncthreads();

        bf16x8 Ah[4], Al[4], Bh[4], Bl[4];
        #pragma unroll
        for (int mi = 0; mi < 4; ++mi) {
            int r = wm * 64 + mi * 16 + lm;
            Ah[mi] = *(const bf16x8*)&As_h[r][quad * 8];
            Al[mi] = *(const bf16x8*)&As_l[r][quad * 8];
        }
        #pragma unroll
        for (int ni = 0; ni < 4; ++ni) {
            int r = wn * 64 + ni * 16 + lm;
            Bh[ni] = *(const bf16x8*)&Bs_h[r][quad * 8];
            Bl[ni] = *(const bf16x8*)&Bs_l[r][quad * 8];
        }
        #pragma unroll
        for (int mi = 0; mi < 4; ++mi)
            #pragma unroll
            for (int ni = 0; ni < 4; ++ni) {
                acc[mi][ni] = __builtin_amdgcn_mfma_f32_16x16x32_bf16(Ah[mi], Bh[ni], acc[mi][ni], 0, 0, 0);
                acc[mi][ni] = __builtin_amdgcn_mfma_f32_16x16x32_bf16(Al[mi], Bh[ni], acc[mi][ni], 0, 0, 0);
                acc[mi][ni] = __builtin_amdgcn_mfma_f32_16x16x32_bf16(Ah[mi], Bl[ni], acc[mi][ni], 0, 0, 0);
            }
        __syncthreads();
    }

    // epilogue: C[row][col] = bf16(acc * dinv[row])
    #pragma unroll
    for (int mi = 0; mi < 4; ++mi) {
        int rbase = bm + wm * 64 + mi * 16 + quad * 4;
        #pragma unroll
        for (int r = 0; r < 4; ++r) {
            int grow = rbase + r;
            if (grow < M) {
                float s = dinv[grow];
                #pragma unroll
                for (int ni = 0; ni < 4; ++ni) {
                    int col = bn + wn * 64 + ni * 16 + lm;
                    C[(size_t)grow * D + col] = (unsigned short)f2bf(acc[mi][ni][r] * s);
                }
            }
        }
    }
}

// ---------------- aggregation: out[d] = relu(dinv[d]*(h'[d] + sum h'[src]) + b) ----
// h' is bf16; one wave per node; lane i owns dims 4i..4i+3 (ushort4 = 8 B/row/lane).
// Latency play: one coalesced load grabs up to 64 edge indices; gathers issued
// 8-at-a-time (independent, all in flight) with __shfl broadcast of indices.

__global__ __launch_bounds__(256) void k_agg(
        const unsigned short* __restrict__ h, const float* __restrict__ dinv,
        const int* __restrict__ row_ptr, const int* __restrict__ col_src,
        const float* __restrict__ bias, float* __restrict__ out, int n) {
    int node = blockIdx.x * 4 + (threadIdx.x >> 6);
    if (node >= n) return;
    int lane = threadIdx.x & 63;
    float di = dinv[node];
    ushort4 sv = ((const ushort4*)(h + (size_t)node * D))[lane];  // self-loop
    float4 acc = make_float4(bf2f(sv.x), bf2f(sv.y), bf2f(sv.z), bf2f(sv.w));
    int beg = row_ptr[node], end = row_ptr[node + 1];

    for (int c = beg; c < end; c += 64) {
        int cnt = min(64, end - c);                       // wave-uniform
        int myidx = (lane < cnt) ? col_src[c + lane] : 0; // one coalesced index load
        int e = 0;
        while (e < cnt) {
            int k = min(8, cnt - e);                      // wave-uniform
            ushort4 v[8];
            #pragma unroll
            for (int j = 0; j < 8; ++j) {
                if (j < k) {
                    int s = __shfl(myidx, e + j);         // broadcast, register-only
                    v[j] = ((const ushort4*)(h + (size_t)s * D))[lane];
                }
            }
            #pragma unroll
            for (int j = 0; j < 8; ++j) {
                if (j < k) {
                    acc.x += bf2f(v[j].x); acc.y += bf2f(v[j].y);
                    acc.z += bf2f(v[j].z); acc.w += bf2f(v[j].w);
                }
            }
            e += k;
        }
    }

    float4 b = ((const float4*)bias)[lane];
    acc.x = fmaxf(acc.x * di + b.x, 0.f);
    acc.y = fmaxf(acc.y * di + b.y, 0.f);
    acc.z = fmaxf(acc.z * di + b.z, 0.f);
    acc.w = fmaxf(acc.w * di + b.w, 0.f);
    ((float4*)(out + (size_t)node * D))[lane] = acc;
}

// ---------------- mean pool, stage 1: chunked sums + atomic flush ----------------
// 64 contiguous nodes per block; batch sorted -> ~1.08 graph spans per block.

__global__ __launch_bounds__(256) void k_pool_sum(
        const float* __restrict__ h, const int* __restrict__ batch,
        float* __restrict__ pooled, int n) {
    int beg = blockIdx.x * 64;
    if (beg >= n) return;
    int end = min(beg + 64, n);
    int t = threadIdx.x;  // dim t
    float acc = 0.f;
    int cur = batch[beg];
    for (int i = beg; i < end; ++i) {
        int g = batch[i];
        if (g != cur) {
            atomicAdd(&pooled[cur * D + t], acc);
            acc = 0.f;
            cur = g;
        }
        acc += h[(size_t)i * D + t];
    }
    atomicAdd(&pooled[cur * D + t], acc);
}

// ---------------- final FC: out[g,o] = bfc[o] + inv_cnt[g] * (pooled_sum[g] . W[:,o]) ----

__global__ void k_fc(const float* __restrict__ pooled, const float* __restrict__ inv_cnt,
                     const float* __restrict__ W, const float* __restrict__ b,
                     float* __restrict__ out) {
    int t = blockIdx.x * blockDim.x + threadIdx.x;
    if (t >= NG * DOUT) return;
    int g = t >> 4, o = t & 15;
    float acc = 0.f;
    for (int k = 0; k < D; ++k) acc += pooled[g * D + k] * W[k * DOUT + o];
    out[t] = acc * inv_cnt[g] + b[o];
}

// ---------------- launch ----------------

extern "C" void kernel_launch(void* const* d_in, const int* in_sizes, int n_in,
                              void* d_out, int out_size, void* d_ws, size_t ws_size,
                              hipStream_t stream) {
    const float* x    = (const float*)d_in[0];
    const int*   eidx = (const int*)d_in[1];
    const int*   batch= (const int*)d_in[2];
    const float* W1   = (const float*)d_in[3];
    const float* b1   = (const float*)d_in[4];
    const float* W2   = (const float*)d_in[5];
    const float* b2   = (const float*)d_in[6];
    const float* W3   = (const float*)d_in[7];
    const float* b3   = (const float*)d_in[8];
    const float* Wfc  = (const float*)d_in[9];
    const float* bfc  = (const float*)d_in[10];
    float* out = (float*)d_out;

    const int n = in_sizes[0] / D;      // 50000
    const int E = in_sizes[1] / 2;      // 400000

    // workspace layout (256B aligned slabs)
    char* p = (char*)d_ws;
    auto take = [&](size_t bytes) -> void* {
        void* q = (void*)p;
        p += (bytes + 255) & ~(size_t)255;
        return q;
    };
    int*   cnt     = (int*)take((size_t)n * 4);
    int*   row_ptr = (int*)take((size_t)(n + 1) * 4);
    int*   cursor  = (int*)take((size_t)n * 4);
    int*   col_src = (int*)take((size_t)E * 4);
    int*   bsums   = (int*)take(256 * 4);
    float* dinv    = (float*)take((size_t)n * 4);
    float* inv_cnt = (float*)take((size_t)NG * 4);
    short* w1hi    = (short*)take((size_t)D * D * 2);
    short* w1lo    = (short*)take((size_t)D * D * 2);
    short* w2hi    = (short*)take((size_t)D * D * 2);
    short* w2lo    = (short*)take((size_t)D * D * 2);
    short* w3hi    = (short*)take((size_t)D * D * 2);
    short* w3lo    = (short*)take((size_t)D * D * 2);
    unsigned short* hbuf = (unsigned short*)take((size_t)n * D * 2);  // bf16 h'
    float* abuf    = (float*)take((size_t)n * D * 4);
    float* pooled  = (float*)take((size_t)NG * D * 4);

    int tb = 256;
    int gn = (n + tb - 1) / tb;
    int ge = (E + tb - 1) / tb;
    int nb = (n + 1023) / 1024;   // 49 scan blocks

    k_zero_cnt<<<gn, tb, 0, stream>>>(cnt, n);
    k_zero_f<<<(NG * D + 255) / 256, 256, 0, stream>>>(pooled, NG * D);
    k_gcnt<<<1, 64, 0, stream>>>(batch, inv_cnt, n);
    k_wsplit<<<D, 256, 0, stream>>>(W1, w1hi, w1lo);
    k_wsplit<<<D, 256, 0, stream>>>(W2, w2hi, w2lo);
    k_wsplit<<<D, 256, 0, stream>>>(W3, w3hi, w3lo);
    k_count<<<ge, tb, 0, stream>>>(eidx, cnt, E);
    k_dinv<<<gn, tb, 0, stream>>>(cnt, dinv, n);
    k_scan1<<<nb, 256, 0, stream>>>(cnt, row_ptr, bsums, n);
    k_scan2<<<1, 64, 0, stream>>>(bsums, nb);
    k_scan3<<<gn, tb, 0, stream>>>(row_ptr, bsums, cursor, n, E);
    k_fill<<<ge, tb, 0, stream>>>(eidx, cursor, col_src, E);

    dim3 ggrid((n + 127) / 128, 2);
    int agrid = (n + 3) / 4;

    k_gemm_mfma<<<ggrid, 256, 0, stream>>>(x, w1hi, w1lo, dinv, hbuf, n);
    k_agg<<<agrid, 256, 0, stream>>>(hbuf, dinv, row_ptr, col_src, b1, abuf, n);

    k_gemm_mfma<<<ggrid, 256, 0, stream>>>(abuf, w2hi, w2lo, dinv, hbuf, n);
    k_agg<<<agrid, 256, 0, stream>>>(hbuf, dinv, row_ptr, col_src, b2, abuf, n);

    k_gemm_mfma<<<ggrid, 256, 0, stream>>>(abuf, w3hi, w3lo, dinv, hbuf, n);
    k_agg<<<agrid, 256, 0, stream>>>(hbuf, dinv, row_ptr, col_src, b3, abuf, n);

    k_pool_sum<<<(n + 63) / 64, 256, 0, stream>>>(abuf, batch, pooled, n);
    k_fc<<<4, 256, 0, stream>>>(pooled, inv_cnt, Wfc, bfc, out);
}